// Round 14
// baseline (199.720 us; speedup 1.0000x reference)
//
#include <hip/hip_runtime.h>
#include <type_traits>

#define D_MODEL 1024
#define NHEADS 16
#define DHEAD 64
#define SEQ 2048
#define BATCH 2
#define MROWS (BATCH*SEQ)   // 4096
#define NQT (SEQ/64)        // 32 q-tiles per (b,h)

typedef unsigned short ushort_t;
typedef unsigned int   u32;
using bf16x8 = __attribute__((ext_vector_type(8))) __bf16;
using bf16x4 = __attribute__((ext_vector_type(4))) __bf16;
using us4    = __attribute__((ext_vector_type(4))) unsigned short;
using us8    = __attribute__((ext_vector_type(8))) unsigned short;
using f32x4  = __attribute__((ext_vector_type(4))) float;
using f32x2  = __attribute__((ext_vector_type(2))) float;

// 0.125 (1/sqrt(DHEAD)) * log2(e): folded into Q so softmax runs in base-2.
#define QSCALE 0.18033688011112042f

__device__ __forceinline__ float fast_exp2(float x) {
#if __has_builtin(__builtin_amdgcn_exp2f)
    return __builtin_amdgcn_exp2f(x);
#else
    return __expf(x * 0.6931471805599453f);
#endif
}

// async global->LDS, 16B per lane; LDS dest is wave-uniform base + lane*16
__device__ __forceinline__ void gl2lds(const ushort_t* g, ushort_t* l) {
    __builtin_amdgcn_global_load_lds(
        (const __attribute__((address_space(1))) unsigned int*)g,
        (__attribute__((address_space(3))) unsigned int*)l,
        16, 0, 0);
}

// ---------------------------------------------------------------------------
// Convert fp32 inputs -> canonical bf16: x (4M) + Wq/Wk/Wv/Wo (1M each) = 8M.
// 8 elements/thread: 2x f32x4 in, 1x 16B bf16x8 out (G13 sweet spot).
// ---------------------------------------------------------------------------
__global__ __launch_bounds__(256) void cvt_kernel(
    const float* __restrict__ x,
    const float* __restrict__ wq, const float* __restrict__ wk,
    const float* __restrict__ wv, const float* __restrict__ wo,
    ushort_t* __restrict__ xb,
    ushort_t* __restrict__ wqb, ushort_t* __restrict__ wkb,
    ushort_t* __restrict__ wvb, ushort_t* __restrict__ wob)
{
    const size_t XN = (size_t)MROWS * D_MODEL;          // 4 Mi
    const size_t WN = (size_t)D_MODEL * D_MODEL;        // 1 Mi
    size_t i = ((size_t)blockIdx.x * 256 + threadIdx.x) * 8;
    const float* s; ushort_t* d; size_t off;
    if (i < XN) { s = x; d = xb; off = i; }
    else {
        size_t j = i - XN;
        int w = (int)(j / WN);
        off = j - (size_t)w * WN;
        s = (w == 0) ? wq : (w == 1) ? wk : (w == 2) ? wv : wo;
        d = (w == 0) ? wqb : (w == 1) ? wkb : (w == 2) ? wvb : wob;
    }
    const f32x4 v0 = *(const f32x4*)(s + off);
    const f32x4 v1 = *(const f32x4*)(s + off + 4);
    bf16x8 o;
    #pragma unroll
    for (int t = 0; t < 4; ++t) o[t] = (__bf16)v0[t];
    #pragma unroll
    for (int t = 0; t < 4; ++t) o[4 + t] = (__bf16)v1[t];
    *(bf16x8*)(d + off) = o;
}

// ---------------------------------------------------------------------------
// NT GEMM v6: Y[M,1024] = A @ W^T + bias (+ residual), tile BM x BN.
// 4 waves, each owns a (BM/2)x(BN/2) quadrant. BK=64 via TWO [rows][32]
// panels. XOR-swizzled LDS 16B slots (phys = logical ^ ((row>>1)&3)) staged
// via permuted per-lane GLOBAL source slot (linear LDS dest, rule
// both-sides-or-neither); read applies the same XOR (r8: conflicts fixed).
// Tile selection (measured): QKV 128x128 (3/CU). out-proj 64x128 (2/CU) —
// r10/r12=195/194.9us; r11's 64x64@4/CU regressed +6.4us (per-FLOP
// LDS/staging traffic dominates occupancy once conflicts are fixed).
// sc: output scale (used for Q pre-scaling: 0.125*log2e).
// ---------------------------------------------------------------------------
template<typename OutT, bool RES, int BM, int BN>
__global__ __launch_bounds__(256, 3) void gemm_nt(
    const ushort_t* __restrict__ A,
    const ushort_t* __restrict__ W0, const ushort_t* __restrict__ W1, const ushort_t* __restrict__ W2,
    const float* __restrict__ b0, const float* __restrict__ b1, const float* __restrict__ b2,
    const float* __restrict__ res,
    OutT* __restrict__ Y0, OutT* __restrict__ Y1, OutT* __restrict__ Y2,
    float qsc)
{
    constexpr int K  = D_MODEL;
    constexpr int MR = BM / 32;           // acc M-repeats per wave (quadrant BM/2)
    constexpr int NR = BN / 32;           // acc N-repeats per wave
    constexpr int CA = BM / 64;           // A-chunks staged per wave (16 rows each)
    constexpr int CW = BN / 64;           // W-chunks staged per wave
    __shared__ ushort_t As[2][BM * 32];   // panel s: k-cols [s*32, s*32+32)
    __shared__ ushort_t Ws[2][BN * 32];

    const int z = blockIdx.z;
    const ushort_t* W  = (z == 0) ? W0 : (z == 1) ? W1 : W2;
    const float* bias  = (z == 0) ? b0 : (z == 1) ? b1 : b2;
    OutT* Y            = (z == 0) ? Y0 : (z == 1) ? Y1 : Y2;
    const float sc     = (z == 0) ? qsc : 1.0f;

    const int i0 = blockIdx.x * BM;
    const int j0 = blockIdx.y * BN;
    const int tid  = threadIdx.x;
    const int lane = tid & 63;
    const int w    = tid >> 6;
    const int wm   = (w >> 1) * (BM / 2);
    const int wn   = (w & 1) * (BN / 2);
    const int l15  = lane & 15;
    const int quad = lane >> 4;

    // staging map: chunk = 16 rows x 32 cols; lane covers row srow, 16B slot
    // lane&3. Source col slot is XOR-permuted so the linear LDS write leaves
    // phys slot p of row r holding logical slot p ^ ((r>>1)&3). Within each
    // 4-lane row-group this permutes the same 64B granule -> coalescing kept.
    const int srow = lane >> 2;                                    // 0..15
    const int scol = ((lane & 3) ^ ((lane >> 3) & 3)) * 8;         // swizzled
    const ushort_t* gA[CA];
    const ushort_t* gW[CW];
    #pragma unroll
    for (int c = 0; c < CA; ++c)
        gA[c] = A + (size_t)(i0 + (w * CA + c) * 16 + srow) * K + scol;
    #pragma unroll
    for (int c = 0; c < CW; ++c)
        gW[c] = W + (size_t)(j0 + (w * CW + c) * 16 + srow) * K + scol;

    // read-side swizzled col offset: rows read are base+l15 (base%16==0),
    // so ((row>>1)&3) == ((l15>>1)&3) -> per-lane constant.
    const int rc = (quad ^ ((l15 >> 1) & 3)) * 8;

    f32x4 acc[MR][NR] = {};  // acc[m][n]: Y rows wm+m*16+l15, cols wn+n*16+quad*4..+3

    for (int k0 = 0; k0 < K; k0 += 64) {
        #pragma unroll
        for (int c = 0; c < CA; ++c) {
            gl2lds(gA[c] + k0,      &As[0][(w * CA + c) * 512]);
            gl2lds(gA[c] + k0 + 32, &As[1][(w * CA + c) * 512]);
        }
        #pragma unroll
        for (int c = 0; c < CW; ++c) {
            gl2lds(gW[c] + k0,      &Ws[0][(w * CW + c) * 512]);
            gl2lds(gW[c] + k0 + 32, &Ws[1][(w * CW + c) * 512]);
        }
        __syncthreads();

        #pragma unroll
        for (int s = 0; s < 2; ++s) {
            bf16x8 af[MR], wf[NR];
            #pragma unroll
            for (int m = 0; m < MR; ++m)
                af[m] = *(const bf16x8*)&As[s][(wm + m * 16 + l15) * 32 + rc];
            #pragma unroll
            for (int n = 0; n < NR; ++n)
                wf[n] = *(const bf16x8*)&Ws[s][(wn + n * 16 + l15) * 32 + rc];
            #pragma unroll
            for (int m = 0; m < MR; ++m)
                #pragma unroll
                for (int n = 0; n < NR; ++n)
                    acc[m][n] = __builtin_amdgcn_mfma_f32_16x16x32_bf16(wf[n], af[m], acc[m][n], 0, 0, 0);
        }
        __syncthreads();
    }

    #pragma unroll
    for (int n = 0; n < NR; ++n) {
        const int col = j0 + wn + n * 16 + quad * 4;
        const f32x4 bv = *(const f32x4*)&bias[col];
        #pragma unroll
        for (int m = 0; m < MR; ++m) {
            const int row = i0 + wm + m * 16 + l15;
            if constexpr (std::is_same<OutT, float>::value) {
                f32x4 v;
                #pragma unroll
                for (int r = 0; r < 4; ++r) v[r] = acc[m][n][r] + bv[r];
                if constexpr (RES) {
                    const f32x4 rv = *(const f32x4*)&res[(size_t)row * D_MODEL + col];
                    #pragma unroll
                    for (int r = 0; r < 4; ++r) v[r] += rv[r];
                }
                *(f32x4*)&Y[(size_t)row * D_MODEL + col] = v;
            } else {
                bf16x4 pk;
                #pragma unroll
                for (int r = 0; r < 4; ++r) pk[r] = (__bf16)((acc[m][n][r] + bv[r]) * sc);
                *(bf16x4*)&Y[(size_t)row * D_MODEL + col] = pk;
            }
        }
    }
}

// ---------------------------------------------------------------------------
// Flash attention v12 (causal): paired q-tiles + k-split + CU-balanced y-map.
//  - Wave runs TWO chains (L/U) over the same staged K/V tile (v11).
//  - Heavy pairs (qp>=8) split into two k-halves; attn_combine merges.
//  - y-map: per-CU triples (y, y+8, y+16) have iters (L, L, 34-2L) = 34 total.
//  NOTE (r9 lesson): do NOT fuse the combine via __threadfence — device-scope
//  fences invalidate the XCD L2 per call and tripled attn's latency.
//  NOTE (r13 lesson): finer chunking (max 12 iters, exact per-CU packing)
//  REGRESSED (+2.7us) — binding constraint is per-iteration serial latency,
//  not drain tail; more blocks = more prologue/partial overhead.
// ---------------------------------------------------------------------------
#define KD 64   // LDS row pitch in elements

__global__ __launch_bounds__(256, 3) void attn_kernel(
    const ushort_t* __restrict__ Qg, const ushort_t* __restrict__ Kg,
    const ushort_t* __restrict__ Vg, ushort_t* __restrict__ Og,
    float* __restrict__ wso, float* __restrict__ wsml)
{
    __shared__ __align__(16) ushort_t Kt[2][64 * KD];   // [key][dim] swizzled
    __shared__ __align__(16) ushort_t Vt[2][64 * KD];   // [dim][key] swizzled
    __shared__ __align__(16) ushort_t Pw[128 * KD];     // [query][key] swizzled, wave-private rows

    const int bh = blockIdx.x;
    const int b = bh >> 4;
    const int h = bh & 15;

    // CU-balanced block decode:
    //  y in [0,8)  : heavy pair qp = 15-y, k-range part 0 (qp+1 iters)
    //  y in [8,16) : heavy pair qp = 15-(y-8), k-range part 1 (qp+1 iters)
    //  y in [16,24): light pair qp = y-16 (2qp+2 iters)
    const int y = blockIdx.y;
    int qp, kt0, kt1, part;
    bool heavy;
    if (y < 16) {
        const int t = y & 7;
        qp = 15 - t;
        part = y >> 3;
        const int nkt = 2 * qp + 2;
        const int hh = qp + 1;
        heavy = true;
        if (part) { kt0 = hh; kt1 = nkt; }
        else      { kt0 = 0;  kt1 = hh;  }
    } else {
        qp = y - 16;            // 0..7
        part = 0;
        kt0 = 0; kt1 = 2 * qp + 2;
        heavy = false;
    }
    const int qtL = 2 * qp;
    const int qtU = 2 * qp + 1;
    const int q0 = qp * 128;

    const int tid  = threadIdx.x;
    const int lane = tid & 63;
    const int w    = tid >> 6;
    const int l15  = lane & 15;
    const int quad = lane >> 4;

    const size_t headoff = (size_t)h * DHEAD;
    const ushort_t* Kbase = Kg + (size_t)(b * SEQ) * D_MODEL + headoff;
    const ushort_t* Vbase = Vg + (size_t)(b * SEQ) * D_MODEL + headoff;

    const int krow = tid >> 3;        // 0..31
    const int kb   = tid & 7;         // 0..7
    const int vkey = tid & 63;
    const int dc0  = tid >> 6;
    const int dc1  = dc0 + 4;

    // hoisted swizzled column offsets (row&7 == l15&7 for all our reads)
    const int rx = (l15 & 7) << 3;
    const int cs0 = (quad * 8) ^ rx;         // cols [0,32) fragment
    const int cs1 = (32 + quad * 8) ^ rx;    // cols [32,64) fragment
    int pwc[4];
    #pragma unroll
    for (int f = 0; f < 4; ++f) pwc[f] = (f * 16 + quad * 4) ^ rx;
    ushort_t* PwRowL = &Pw[(w * 16 + l15) * KD];
    ushort_t* PwRowU = &Pw[(64 + w * 16 + l15) * KD];

    // Kt staging addresses (krow&7 == (krow+32)&7)
    const int kwa = krow * KD + ((kb * 8) ^ ((krow & 7) << 3));

    const int qgL = q0 + w * 16 + l15;
    const int qgU = q0 + 64 + w * 16 + l15;
    const size_t qrowL = (size_t)(b * SEQ + qgL) * D_MODEL + headoff;
    const size_t qrowU = (size_t)(b * SEQ + qgU) * D_MODEL + headoff;
    const bf16x8 qf0L = *(const bf16x8*)&Qg[qrowL + quad * 8];
    const bf16x8 qf1L = *(const bf16x8*)&Qg[qrowL + 32 + quad * 8];
    const bf16x8 qf0U = *(const bf16x8*)&Qg[qrowU + quad * 8];
    const bf16x8 qf1U = *(const bf16x8*)&Qg[qrowU + 32 + quad * 8];

    bf16x8 onesf;
    #pragma unroll
    for (int j = 0; j < 8; ++j) onesf[j] = (__bf16)1.0f;

    float m_runL = -1e30f, m_runU = -1e30f;
    f32x4 oL[4] = {}, oU[4] = {};
    f32x4 o4L = {}, o4U = {};

    us8 kp0, kp1, vp0, vp1;
    const size_t koff0 = (size_t)(kt0 * 64) * D_MODEL;
    kp0 = *(const us8*)&Kbase[koff0 + (size_t)krow * D_MODEL + kb * 8];
    kp1 = *(const us8*)&Kbase[koff0 + (size_t)(32 + krow) * D_MODEL + kb * 8];
    vp0 = *(const us8*)&Vbase[koff0 + (size_t)vkey * D_MODEL + dc0 * 8];
    vp1 = *(const us8*)&Vbase[koff0 + (size_t)vkey * D_MODEL + dc1 * 8];
    *(us8*)&Kt[0][kwa]           = kp0;
    *(us8*)&Kt[0][kwa + 32 * KD] = kp1;
    #pragma unroll
    for (int j = 0; j < 8; ++j) {
        Vt[0][(dc0 * 8 + j) * KD + (vkey ^ (j << 3))] = vp0[j];
        Vt[0][(dc1 * 8 + j) * KD + (vkey ^ (j << 3))] = vp1[j];
    }
    __syncthreads();

    for (int kt = kt0; kt < kt1; ++kt) {
        const int cur = (kt - kt0) & 1;
        const int nxt = cur ^ 1;
        const bool pre = (kt + 1 < kt1);
        const bool actL = (kt <= qtL);   // block-uniform; false only on last global iter
        if (pre) {
            const size_t koff = (size_t)((kt + 1) * 64) * D_MODEL;
            kp0 = *(const us8*)&Kbase[koff + (size_t)krow * D_MODEL + kb * 8];
            kp1 = *(const us8*)&Kbase[koff + (size_t)(32 + krow) * D_MODEL + kb * 8];
            vp0 = *(const us8*)&Vbase[koff + (size_t)vkey * D_MODEL + dc0 * 8];
            vp1 = *(const us8*)&Vbase[koff + (size_t)vkey * D_MODEL + dc1 * 8];
        }

        // ---- QK^T (S^T = K Q^T), both chains share kf reads ----
        f32x4 svL[4], svU[4];
        __builtin_amdgcn_s_setprio(1);
        #pragma unroll
        for (int f = 0; f < 4; ++f) {
            const int rbase = (f * 16 + l15) * KD;
            const bf16x8 kf0 = *(const bf16x8*)&Kt[cur][rbase + cs0];
            const bf16x8 kf1 = *(const bf16x8*)&Kt[cur][rbase + cs1];
            f32x4 sU = {};
            sU = __builtin_amdgcn_mfma_f32_16x16x32_bf16(kf0, qf0U, sU, 0, 0, 0);
            sU = __builtin_amdgcn_mfma_f32_16x16x32_bf16(kf1, qf1U, sU, 0, 0, 0);
            svU[f] = sU;
            f32x4 sL = {};
            sL = __builtin_amdgcn_mfma_f32_16x16x32_bf16(kf0, qf0L, sL, 0, 0, 0);
            sL = __builtin_amdgcn_mfma_f32_16x16x32_bf16(kf1, qf1L, sL, 0, 0, 0);
            svL[f] = sL;
        }
        __builtin_amdgcn_s_setprio(0);

        // causal masks (diagonal tiles only; scale pre-folded into Q)
        if (kt == qtU) {
            #pragma unroll
            for (int f = 0; f < 4; ++f)
                #pragma unroll
                for (int r = 0; r < 4; ++r) {
                    const int kg = kt * 64 + f * 16 + quad * 4 + r;
                    svU[f][r] = (kg <= qgU) ? svU[f][r] : -1e30f;
                }
        }
        if (kt == qtL) {
            #pragma unroll
            for (int f = 0; f < 4; ++f)
                #pragma unroll
                for (int r = 0; r < 4; ++r) {
                    const int kg = kt * 64 + f * 16 + quad * 4 + r;
                    svL[f][r] = (kg <= qgL) ? svL[f][r] : -1e30f;
                }
        }

        // ---- online softmax (base-2) with defer-max, chain U ----
        {
            float mf[4];
            #pragma unroll
            for (int f = 0; f < 4; ++f)
                mf[f] = fmaxf(fmaxf(svU[f][0], svU[f][1]), fmaxf(svU[f][2], svU[f][3]));
            float mx = fmaxf(fmaxf(mf[0], mf[1]), fmaxf(mf[2], mf[3]));
            mx = fmaxf(mx, __shfl_xor(mx, 16));
            mx = fmaxf(mx, __shfl_xor(mx, 32));
            if (!__all(mx <= m_runU + 8.0f)) {
                const float mn = fmaxf(m_runU, mx);
                const float al = fast_exp2(m_runU - mn);
                m_runU = mn;
                #pragma unroll
                for (int t = 0; t < 4; ++t)
                    #pragma unroll
                    for (int r = 0; r < 4; ++r) oU[t][r] *= al;
                o4U[0] *= al;
            }
            #pragma unroll
            for (int f = 0; f < 4; ++f) {
                bf16x4 pk;
                #pragma unroll
                for (int r = 0; r < 4; ++r)
                    pk[r] = (__bf16)fast_exp2(svU[f][r] - m_runU);
                *(bf16x4*)&PwRowU[pwc[f]] = pk;
            }
        }
        // ---- chain L softmax (skipped on final global iter) ----
        if (actL) {
            float mf[4];
            #pragma unroll
            for (int f = 0; f < 4; ++f)
                mf[f] = fmaxf(fmaxf(svL[f][0], svL[f][1]), fmaxf(svL[f][2], svL[f][3]));
            float mx = fmaxf(fmaxf(mf[0], mf[1]), fmaxf(mf[2], mf[3]));
            mx = fmaxf(mx, __shfl_xor(mx, 16));
            mx = fmaxf(mx, __shfl_xor(mx, 32));
            if (!__all(mx <= m_runL + 8.0f)) {
                const float mn = fmaxf(m_runL, mx);
                const float al = fast_exp2(m_runL - mn);
                m_runL = mn;
                #pragma unroll
                for (int t = 0; t < 4; ++t)
                    #pragma unroll
                    for (int r = 0; r < 4; ++r) oL[t][r] *= al;
                o4L[0] *= al;
            }
            #pragma unroll
            for (int f = 0; f < 4; ++f) {
                bf16x4 pk;
                #pragma unroll
                for (int r = 0; r < 4; ++r)
                    pk[r] = (__bf16)fast_exp2(svL[f][r] - m_runL);
                *(bf16x4*)&PwRowL[pwc[f]] = pk;
            }
        }
        __asm__ volatile("s_waitcnt lgkmcnt(0)" ::: "memory");

        // ---- O^T += V^T P^T (vf shared by both chains); l via ones-MFMA ----
        __builtin_amdgcn_s_setprio(1);
        #pragma unroll
        for (int s = 0; s < 2; ++s) {
            const int cc = s ? cs1 : cs0;
            const bf16x8 pfU = *(const bf16x8*)&PwRowU[cc];
            if (actL) {
                const bf16x8 pfL = *(const bf16x8*)&PwRowL[cc];
                #pragma unroll
                for (int t = 0; t < 4; ++t) {
                    const bf16x8 vf = *(const bf16x8*)&Vt[cur][(t * 16 + l15) * KD + cc];
                    oU[t] = __builtin_amdgcn_mfma_f32_16x16x32_bf16(vf, pfU, oU[t], 0, 0, 0);
                    oL[t] = __builtin_amdgcn_mfma_f32_16x16x32_bf16(vf, pfL, oL[t], 0, 0, 0);
                }
                o4U = __builtin_amdgcn_mfma_f32_16x16x32_bf16(onesf, pfU, o4U, 0, 0, 0);
                o4L = __builtin_amdgcn_mfma_f32_16x16x32_bf16(onesf, pfL, o4L, 0, 0, 0);
            } else {
                #pragma unroll
                for (int t = 0; t < 4; ++t) {
                    const bf16x8 vf = *(const bf16x8*)&Vt[cur][(t * 16 + l15) * KD + cc];
                    oU[t] = __builtin_amdgcn_mfma_f32_16x16x32_bf16(vf, pfU, oU[t], 0, 0, 0);
                }
                o4U = __builtin_amdgcn_mfma_f32_16x16x32_bf16(onesf, pfU, o4U, 0, 0, 0);
            }
        }
        __builtin_amdgcn_s_setprio(0);

        if (pre) {
            *(us8*)&Kt[nxt][kwa]           = kp0;
            *(us8*)&Kt[nxt][kwa + 32 * KD] = kp1;
            #pragma unroll
            for (int j = 0; j < 8; ++j) {
                Vt[nxt][(dc0 * 8 + j) * KD + (vkey ^ (j << 3))] = vp0[j];
                Vt[nxt][(dc1 * 8 + j) * KD + (vkey ^ (j << 3))] = vp1[j];
            }
        }
        __asm__ volatile("s_waitcnt lgkmcnt(0)\n\ts_barrier" ::: "memory");
    }

    if (!heavy) {
        const float invL = 1.f / o4L[0];
        const float invU = 1.f / o4U[0];
        const size_t orowL = (size_t)(b * SEQ + qgL) * D_MODEL + headoff;
        const size_t orowU = (size_t)(b * SEQ + qgU) * D_MODEL + headoff;
        #pragma unroll
        for (int t = 0; t < 4; ++t) {
            bf16x4 pkL, pkU;
            #pragma unroll
            for (int r = 0; r < 4; ++r) {
                pkL[r] = (__bf16)(oL[t][r] * invL);
                pkU[r] = (__bf16)(oU[t][r] * invU);
            }
            *(bf16x4*)&Og[orowL + t * 16 + quad * 4] = pkL;
            *(bf16x4*)&Og[orowU + t * 16 + quad * 4] = pkU;
        }
    } else {
        // partial: unnormalized fp32 O + (m, l) to workspace; 128 rows/tile
        const int T = (bh * 8 + (qp - 8)) * 2 + part;
        const int rL = w * 16 + l15;
        const int rU = 64 + w * 16 + l15;
        float* wo = wso + (size_t)T * 8192;
        #pragma unroll
        for (int t = 0; t < 4; ++t) {
            *(f32x4*)&wo[(size_t)rL * 64 + t * 16 + quad * 4] = oL[t];
            *(f32x4*)&wo[(size_t)rU * 64 + t * 16 + quad * 4] = oU[t];
        }
        if (quad == 0) {
            f32x2 mlL = { m_runL, o4L[0] };
            f32x2 mlU = { m_runU, o4U[0] };
            *(f32x2*)&wsml[(size_t)(T * 128 + rL) * 2] = mlL;
            *(f32x2*)&wsml[(size_t)(T * 128 + rU) * 2] = mlU;
        }
    }
}

// ---------------------------------------------------------------------------
// Combine the two k-split partials for heavy q-pairs (base-2 domain).
// 32768 rows x 64 dims; thread = (row, 4 dims). Heavy rows: q in [1024,2048).
// ---------------------------------------------------------------------------
__global__ __launch_bounds__(256) void attn_combine(
    const float* __restrict__ wso, const float* __restrict__ wsml,
    ushort_t* __restrict__ Og)
{
    const int gid = blockIdx.x * 256 + threadIdx.x;
    const int row = gid >> 4;          // 0..32767
    const int dp  = (gid & 15) * 4;
    const int bh  = row >> 10;
    const int rr  = row & 1023;        // row within heavy region
    const int qph = rr >> 7;           // heavy pair index 0..7 (qp = 8+qph)
    const int q   = rr & 127;
    const int T0  = (bh * 8 + qph) * 2;

    const f32x2 ml0 = *(const f32x2*)&wsml[(size_t)(T0 * 128 + q) * 2];
    const f32x2 ml1 = *(const f32x2*)&wsml[(size_t)((T0 + 1) * 128 + q) * 2];
    const float M  = fmaxf(ml0[0], ml1[0]);
    const float a0 = fast_exp2(ml0[0] - M);
    const float a1 = fast_exp2(ml1[0] - M);
    const float inv = 1.0f / (ml0[1] * a0 + ml1[1] * a1);

    const f32x4 o0 = *(const f32x4*)&wso[(size_t)T0 * 8192 + q * 64 + dp];
    const f32x4 o1 = *(const f32x4*)&wso[(size_t)(T0 + 1) * 8192 + q * 64 + dp];

    const int b = bh >> 4;
    const int h = bh & 15;
    const int qg = 1024 + rr;          // q-rows [1024, 2048)
    bf16x4 pk;
    #pragma unroll
    for (int r = 0; r < 4; ++r)
        pk[r] = (__bf16)((o0[r] * a0 + o1[r] * a1) * inv);
    *(bf16x4*)&Og[(size_t)(b * SEQ + qg) * D_MODEL + h * DHEAD + dp] = pk;
}

// ---------------------------------------------------------------------------
// LayerNorm over last dim (1024), one block per row, fp32 in/out (in-place ok).
// ---------------------------------------------------------------------------
__global__ __launch_bounds__(256) void ln_kernel(
    const float* __restrict__ X, const float* __restrict__ g,
    const float* __restrict__ bta, float* __restrict__ out)
{
    __shared__ float r1[4], r2[4];
    const int row = blockIdx.x;
    const int tid = threadIdx.x;
    const float* p = X + (size_t)row * D_MODEL;
    float v[4]; float s1 = 0.f, s2 = 0.f;
    #pragma unroll
    for (int i = 0; i < 4; ++i) { v[i] = p[tid + 256 * i]; s1 += v[i]; s2 += v[i] * v[i]; }
    #pragma unroll
    for (int d = 32; d >= 1; d >>= 1) { s1 += __shfl_xor(s1, d); s2 += __shfl_xor(s2, d); }
    if ((tid & 63) == 0) { r1[tid >> 6] = s1; r2[tid >> 6] = s2; }
    __syncthreads();
    s1 = r1[0] + r1[1] + r1[2] + r1[3];
    s2 = r2[0] + r2[1] + r2[2] + r2[3];
    const float mu  = s1 * (1.f / D_MODEL);
    const float var = s2 * (1.f / D_MODEL) - mu * mu;
    const float rstd = rsqrtf(var + 1e-5f);
    #pragma unroll
    for (int i = 0; i < 4; ++i) {
        const int c = tid + 256 * i;
        out[(size_t)row * D_MODEL + c] = (v[i] - mu) * rstd * g[c] + bta[c];
    }
}

extern "C" void kernel_launch(void* const* d_in, const int* in_sizes, int n_in,
                              void* d_out, int out_size, void* d_ws, size_t ws_size,
                              hipStream_t stream) {
    const float* x     = (const float*)d_in[0];
    const float* Wq    = (const float*)d_in[1];
    const float* bq    = (const float*)d_in[2];
    const float* Wk    = (const float*)d_in[3];
    const float* bk    = (const float*)d_in[4];
    const float* Wv    = (const float*)d_in[5];
    const float* bv    = (const float*)d_in[6];
    const float* Wo    = (const float*)d_in[7];
    const float* bo    = (const float*)d_in[8];
    const float* gamma = (const float*)d_in[9];
    const float* beta  = (const float*)d_in[10];

    const size_t XN = (size_t)MROWS * D_MODEL;      // 4 Mi elements
    const size_t WN = (size_t)D_MODEL * D_MODEL;    // 1 Mi elements
    ushort_t* wsp = (ushort_t*)d_ws;
    ushort_t* xb  = wsp;
    ushort_t* Yq  = wsp + XN;
    ushort_t* Yk  = wsp + 2 * XN;
    ushort_t* Yv  = wsp + 3 * XN;
    ushort_t* Wqb = wsp + 4 * XN;
    ushort_t* Wkb = Wqb + WN;
    ushort_t* Wvb = Wkb + WN;
    ushort_t* Wob = Wvb + WN;
    ushort_t* ctx = xb;                 // overlay: xb dead after QKV gemm
    float*    pre = (float*)d_out;      // fp32 pre-LN lives in d_out; LN in-place

    // k-split partial buffers: after the bf16 region (40 MB).
    // wso: 512 tiles x 128 q x 64 d fp32 = 16 MB; wsml: 512 x 128 x {m,l} = 512 KB.
    float* wso  = (float*)(wsp + 4 * XN + 4 * WN);
    float* wsml = wso + (size_t)512 * 8192;

    cvt_kernel<<<dim3(4096), 256, 0, stream>>>(x, Wq, Wk, Wv, Wo, xb, Wqb, Wkb, Wvb, Wob);

    gemm_nt<ushort_t, false, 128, 128><<<dim3(MROWS / 128, D_MODEL / 128, 3), 256, 0, stream>>>(
        xb, Wqb, Wkb, Wvb, bq, bk, bv, nullptr, Yq, Yk, Yv, QSCALE);

    attn_kernel<<<dim3(BATCH * NHEADS, 24), 256, 0, stream>>>(Yq, Yk, Yv, ctx, wso, wsml);

    attn_combine<<<dim3(2048), 256, 0, stream>>>(wso, wsml, ctx);

    gemm_nt<float, true, 64, 128><<<dim3(MROWS / 64, D_MODEL / 128, 1), 256, 0, stream>>>(
        ctx, Wob, Wob, Wob, bo, bo, bo, x, pre, pre, pre, 1.0f);

    ln_kernel<<<dim3(MROWS), 256, 0, stream>>>(pre, gamma, beta, (float*)d_out);
}

// Round 15
// 192.625 us; speedup vs baseline: 1.0368x; 1.0368x over previous
//
#include <hip/hip_runtime.h>
#include <type_traits>

#define D_MODEL 1024
#define NHEADS 16
#define DHEAD 64
#define SEQ 2048
#define BATCH 2
#define MROWS (BATCH*SEQ)   // 4096
#define NQT (SEQ/64)        // 32 q-tiles per (b,h)

typedef unsigned short ushort_t;
typedef unsigned int   u32;
using bf16x8 = __attribute__((ext_vector_type(8))) __bf16;
using bf16x4 = __attribute__((ext_vector_type(4))) __bf16;
using us4    = __attribute__((ext_vector_type(4))) unsigned short;
using us8    = __attribute__((ext_vector_type(8))) unsigned short;
using f32x4  = __attribute__((ext_vector_type(4))) float;
using f32x2  = __attribute__((ext_vector_type(2))) float;

// 0.125 (1/sqrt(DHEAD)) * log2(e): folded into Q so softmax runs in base-2.
#define QSCALE 0.18033688011112042f

__device__ __forceinline__ float fast_exp2(float x) {
#if __has_builtin(__builtin_amdgcn_exp2f)
    return __builtin_amdgcn_exp2f(x);
#else
    return __expf(x * 0.6931471805599453f);
#endif
}

// async global->LDS, 16B per lane; LDS dest is wave-uniform base + lane*16
__device__ __forceinline__ void gl2lds(const ushort_t* g, ushort_t* l) {
    __builtin_amdgcn_global_load_lds(
        (const __attribute__((address_space(1))) unsigned int*)g,
        (__attribute__((address_space(3))) unsigned int*)l,
        16, 0, 0);
}

// ---------------------------------------------------------------------------
// Convert fp32 inputs -> canonical bf16: x (4M) + Wq/Wk/Wv/Wo (1M each) = 8M.
// 8 elements/thread: 2x f32x4 in, 1x 16B bf16x8 out (G13 sweet spot).
// ---------------------------------------------------------------------------
__global__ __launch_bounds__(256) void cvt_kernel(
    const float* __restrict__ x,
    const float* __restrict__ wq, const float* __restrict__ wk,
    const float* __restrict__ wv, const float* __restrict__ wo,
    ushort_t* __restrict__ xb,
    ushort_t* __restrict__ wqb, ushort_t* __restrict__ wkb,
    ushort_t* __restrict__ wvb, ushort_t* __restrict__ wob)
{
    const size_t XN = (size_t)MROWS * D_MODEL;          // 4 Mi
    const size_t WN = (size_t)D_MODEL * D_MODEL;        // 1 Mi
    size_t i = ((size_t)blockIdx.x * 256 + threadIdx.x) * 8;
    const float* s; ushort_t* d; size_t off;
    if (i < XN) { s = x; d = xb; off = i; }
    else {
        size_t j = i - XN;
        int w = (int)(j / WN);
        off = j - (size_t)w * WN;
        s = (w == 0) ? wq : (w == 1) ? wk : (w == 2) ? wv : wo;
        d = (w == 0) ? wqb : (w == 1) ? wkb : (w == 2) ? wvb : wob;
    }
    const f32x4 v0 = *(const f32x4*)(s + off);
    const f32x4 v1 = *(const f32x4*)(s + off + 4);
    bf16x8 o;
    #pragma unroll
    for (int t = 0; t < 4; ++t) o[t] = (__bf16)v0[t];
    #pragma unroll
    for (int t = 0; t < 4; ++t) o[4 + t] = (__bf16)v1[t];
    *(bf16x8*)(d + off) = o;
}

// ---------------------------------------------------------------------------
// NT GEMM v6: Y[M,1024] = A @ W^T + bias (+ residual), tile BM x BN.
// 4 waves, each owns a (BM/2)x(BN/2) quadrant. BK=64 via TWO [rows][32]
// panels. XOR-swizzled LDS 16B slots (phys = logical ^ ((row>>1)&3)) staged
// via permuted per-lane GLOBAL source slot (linear LDS dest, rule
// both-sides-or-neither); read applies the same XOR (r8: conflicts 4.7M->~0).
// Tile selection (measured): QKV 128x128 (3/CU). out-proj 64x128 (2/CU) —
// r10/r12=195/194.9us; r11's 64x64@4/CU regressed +6.4us (per-FLOP
// LDS/staging traffic dominates occupancy once conflicts are fixed).
// sc: output scale (used for Q pre-scaling: 0.125*log2e).
// ---------------------------------------------------------------------------
template<typename OutT, bool RES, int BM, int BN>
__global__ __launch_bounds__(256, 3) void gemm_nt(
    const ushort_t* __restrict__ A,
    const ushort_t* __restrict__ W0, const ushort_t* __restrict__ W1, const ushort_t* __restrict__ W2,
    const float* __restrict__ b0, const float* __restrict__ b1, const float* __restrict__ b2,
    const float* __restrict__ res,
    OutT* __restrict__ Y0, OutT* __restrict__ Y1, OutT* __restrict__ Y2,
    float qsc)
{
    constexpr int K  = D_MODEL;
    constexpr int MR = BM / 32;           // acc M-repeats per wave (quadrant BM/2)
    constexpr int NR = BN / 32;           // acc N-repeats per wave
    constexpr int CA = BM / 64;           // A-chunks staged per wave (16 rows each)
    constexpr int CW = BN / 64;           // W-chunks staged per wave
    __shared__ ushort_t As[2][BM * 32];   // panel s: k-cols [s*32, s*32+32)
    __shared__ ushort_t Ws[2][BN * 32];

    const int z = blockIdx.z;
    const ushort_t* W  = (z == 0) ? W0 : (z == 1) ? W1 : W2;
    const float* bias  = (z == 0) ? b0 : (z == 1) ? b1 : b2;
    OutT* Y            = (z == 0) ? Y0 : (z == 1) ? Y1 : Y2;
    const float sc     = (z == 0) ? qsc : 1.0f;

    const int i0 = blockIdx.x * BM;
    const int j0 = blockIdx.y * BN;
    const int tid  = threadIdx.x;
    const int lane = tid & 63;
    const int w    = tid >> 6;
    const int wm   = (w >> 1) * (BM / 2);
    const int wn   = (w & 1) * (BN / 2);
    const int l15  = lane & 15;
    const int quad = lane >> 4;

    // staging map: chunk = 16 rows x 32 cols; lane covers row srow, 16B slot
    // lane&3. Source col slot is XOR-permuted so the linear LDS write leaves
    // phys slot p of row r holding logical slot p ^ ((r>>1)&3). Within each
    // 4-lane row-group this permutes the same 64B granule -> coalescing kept.
    const int srow = lane >> 2;                                    // 0..15
    const int scol = ((lane & 3) ^ ((lane >> 3) & 3)) * 8;         // swizzled
    const ushort_t* gA[CA];
    const ushort_t* gW[CW];
    #pragma unroll
    for (int c = 0; c < CA; ++c)
        gA[c] = A + (size_t)(i0 + (w * CA + c) * 16 + srow) * K + scol;
    #pragma unroll
    for (int c = 0; c < CW; ++c)
        gW[c] = W + (size_t)(j0 + (w * CW + c) * 16 + srow) * K + scol;

    // read-side swizzled col offset: rows read are base+l15 (base%16==0),
    // so ((row>>1)&3) == ((l15>>1)&3) -> per-lane constant.
    const int rc = (quad ^ ((l15 >> 1) & 3)) * 8;

    f32x4 acc[MR][NR] = {};  // acc[m][n]: Y rows wm+m*16+l15, cols wn+n*16+quad*4..+3

    for (int k0 = 0; k0 < K; k0 += 64) {
        #pragma unroll
        for (int c = 0; c < CA; ++c) {
            gl2lds(gA[c] + k0,      &As[0][(w * CA + c) * 512]);
            gl2lds(gA[c] + k0 + 32, &As[1][(w * CA + c) * 512]);
        }
        #pragma unroll
        for (int c = 0; c < CW; ++c) {
            gl2lds(gW[c] + k0,      &Ws[0][(w * CW + c) * 512]);
            gl2lds(gW[c] + k0 + 32, &Ws[1][(w * CW + c) * 512]);
        }
        __syncthreads();

        #pragma unroll
        for (int s = 0; s < 2; ++s) {
            bf16x8 af[MR], wf[NR];
            #pragma unroll
            for (int m = 0; m < MR; ++m)
                af[m] = *(const bf16x8*)&As[s][(wm + m * 16 + l15) * 32 + rc];
            #pragma unroll
            for (int n = 0; n < NR; ++n)
                wf[n] = *(const bf16x8*)&Ws[s][(wn + n * 16 + l15) * 32 + rc];
            #pragma unroll
            for (int m = 0; m < MR; ++m)
                #pragma unroll
                for (int n = 0; n < NR; ++n)
                    acc[m][n] = __builtin_amdgcn_mfma_f32_16x16x32_bf16(wf[n], af[m], acc[m][n], 0, 0, 0);
        }
        __syncthreads();
    }

    #pragma unroll
    for (int n = 0; n < NR; ++n) {
        const int col = j0 + wn + n * 16 + quad * 4;
        const f32x4 bv = *(const f32x4*)&bias[col];
        #pragma unroll
        for (int m = 0; m < MR; ++m) {
            const int row = i0 + wm + m * 16 + l15;
            if constexpr (std::is_same<OutT, float>::value) {
                f32x4 v;
                #pragma unroll
                for (int r = 0; r < 4; ++r) v[r] = acc[m][n][r] + bv[r];
                if constexpr (RES) {
                    const f32x4 rv = *(const f32x4*)&res[(size_t)row * D_MODEL + col];
                    #pragma unroll
                    for (int r = 0; r < 4; ++r) v[r] += rv[r];
                }
                *(f32x4*)&Y[(size_t)row * D_MODEL + col] = v;
            } else {
                bf16x4 pk;
                #pragma unroll
                for (int r = 0; r < 4; ++r) pk[r] = (__bf16)((acc[m][n][r] + bv[r]) * sc);
                *(bf16x4*)&Y[(size_t)row * D_MODEL + col] = pk;
            }
        }
    }
}

// ---------------------------------------------------------------------------
// Flash attention v12 (causal): paired q-tiles + k-split + CU-balanced y-map.
//  - Wave runs TWO chains (L/U) over the same staged K/V tile (v11).
//  - Heavy pairs (qp>=8) split into two k-halves; attn_combine merges.
//  - y-map: per-CU triples (y, y+8, y+16) have iters (L, L, 34-2L) = 34 total.
//  NOTE (r9 lesson): do NOT fuse the combine via __threadfence — device-scope
//  fences invalidate the XCD L2 per call and tripled attn's latency.
//  NOTE (r13 lesson): finer chunking (max 12 iters, exact per-CU packing)
//  REGRESSED (+2.7us) — binding constraint is per-iteration serial latency
//  (QK -> softmax -> P LDS round-trip -> PV), not drain tail. Next lever
//  would be T12 in-register P-handoff (cvt_pk + cross-quad shuffle).
// ---------------------------------------------------------------------------
#define KD 64   // LDS row pitch in elements

__global__ __launch_bounds__(256, 3) void attn_kernel(
    const ushort_t* __restrict__ Qg, const ushort_t* __restrict__ Kg,
    const ushort_t* __restrict__ Vg, ushort_t* __restrict__ Og,
    float* __restrict__ wso, float* __restrict__ wsml)
{
    __shared__ __align__(16) ushort_t Kt[2][64 * KD];   // [key][dim] swizzled
    __shared__ __align__(16) ushort_t Vt[2][64 * KD];   // [dim][key] swizzled
    __shared__ __align__(16) ushort_t Pw[128 * KD];     // [query][key] swizzled, wave-private rows

    const int bh = blockIdx.x;
    const int b = bh >> 4;
    const int h = bh & 15;

    // CU-balanced block decode:
    //  y in [0,8)  : heavy pair qp = 15-y, k-range part 0 (qp+1 iters)
    //  y in [8,16) : heavy pair qp = 15-(y-8), k-range part 1 (qp+1 iters)
    //  y in [16,24): light pair qp = y-16 (2qp+2 iters)
    const int y = blockIdx.y;
    int qp, kt0, kt1, part;
    bool heavy;
    if (y < 16) {
        const int t = y & 7;
        qp = 15 - t;
        part = y >> 3;
        const int nkt = 2 * qp + 2;
        const int hh = qp + 1;
        heavy = true;
        if (part) { kt0 = hh; kt1 = nkt; }
        else      { kt0 = 0;  kt1 = hh;  }
    } else {
        qp = y - 16;            // 0..7
        part = 0;
        kt0 = 0; kt1 = 2 * qp + 2;
        heavy = false;
    }
    const int qtL = 2 * qp;
    const int qtU = 2 * qp + 1;
    const int q0 = qp * 128;

    const int tid  = threadIdx.x;
    const int lane = tid & 63;
    const int w    = tid >> 6;
    const int l15  = lane & 15;
    const int quad = lane >> 4;

    const size_t headoff = (size_t)h * DHEAD;
    const ushort_t* Kbase = Kg + (size_t)(b * SEQ) * D_MODEL + headoff;
    const ushort_t* Vbase = Vg + (size_t)(b * SEQ) * D_MODEL + headoff;

    const int krow = tid >> 3;        // 0..31
    const int kb   = tid & 7;         // 0..7
    const int vkey = tid & 63;
    const int dc0  = tid >> 6;
    const int dc1  = dc0 + 4;

    // hoisted swizzled column offsets (row&7 == l15&7 for all our reads)
    const int rx = (l15 & 7) << 3;
    const int cs0 = (quad * 8) ^ rx;         // cols [0,32) fragment
    const int cs1 = (32 + quad * 8) ^ rx;    // cols [32,64) fragment
    int pwc[4];
    #pragma unroll
    for (int f = 0; f < 4; ++f) pwc[f] = (f * 16 + quad * 4) ^ rx;
    ushort_t* PwRowL = &Pw[(w * 16 + l15) * KD];
    ushort_t* PwRowU = &Pw[(64 + w * 16 + l15) * KD];

    // Kt staging addresses (krow&7 == (krow+32)&7)
    const int kwa = krow * KD + ((kb * 8) ^ ((krow & 7) << 3));

    const int qgL = q0 + w * 16 + l15;
    const int qgU = q0 + 64 + w * 16 + l15;
    const size_t qrowL = (size_t)(b * SEQ + qgL) * D_MODEL + headoff;
    const size_t qrowU = (size_t)(b * SEQ + qgU) * D_MODEL + headoff;
    const bf16x8 qf0L = *(const bf16x8*)&Qg[qrowL + quad * 8];
    const bf16x8 qf1L = *(const bf16x8*)&Qg[qrowL + 32 + quad * 8];
    const bf16x8 qf0U = *(const bf16x8*)&Qg[qrowU + quad * 8];
    const bf16x8 qf1U = *(const bf16x8*)&Qg[qrowU + 32 + quad * 8];

    bf16x8 onesf;
    #pragma unroll
    for (int j = 0; j < 8; ++j) onesf[j] = (__bf16)1.0f;

    float m_runL = -1e30f, m_runU = -1e30f;
    f32x4 oL[4] = {}, oU[4] = {};
    f32x4 o4L = {}, o4U = {};

    us8 kp0, kp1, vp0, vp1;
    const size_t koff0 = (size_t)(kt0 * 64) * D_MODEL;
    kp0 = *(const us8*)&Kbase[koff0 + (size_t)krow * D_MODEL + kb * 8];
    kp1 = *(const us8*)&Kbase[koff0 + (size_t)(32 + krow) * D_MODEL + kb * 8];
    vp0 = *(const us8*)&Vbase[koff0 + (size_t)vkey * D_MODEL + dc0 * 8];
    vp1 = *(const us8*)&Vbase[koff0 + (size_t)vkey * D_MODEL + dc1 * 8];
    *(us8*)&Kt[0][kwa]           = kp0;
    *(us8*)&Kt[0][kwa + 32 * KD] = kp1;
    #pragma unroll
    for (int j = 0; j < 8; ++j) {
        Vt[0][(dc0 * 8 + j) * KD + (vkey ^ (j << 3))] = vp0[j];
        Vt[0][(dc1 * 8 + j) * KD + (vkey ^ (j << 3))] = vp1[j];
    }
    __syncthreads();

    for (int kt = kt0; kt < kt1; ++kt) {
        const int cur = (kt - kt0) & 1;
        const int nxt = cur ^ 1;
        const bool pre = (kt + 1 < kt1);
        const bool actL = (kt <= qtL);   // block-uniform; false only on last global iter
        if (pre) {
            const size_t koff = (size_t)((kt + 1) * 64) * D_MODEL;
            kp0 = *(const us8*)&Kbase[koff + (size_t)krow * D_MODEL + kb * 8];
            kp1 = *(const us8*)&Kbase[koff + (size_t)(32 + krow) * D_MODEL + kb * 8];
            vp0 = *(const us8*)&Vbase[koff + (size_t)vkey * D_MODEL + dc0 * 8];
            vp1 = *(const us8*)&Vbase[koff + (size_t)vkey * D_MODEL + dc1 * 8];
        }

        // ---- QK^T (S^T = K Q^T), both chains share kf reads ----
        f32x4 svL[4], svU[4];
        __builtin_amdgcn_s_setprio(1);
        #pragma unroll
        for (int f = 0; f < 4; ++f) {
            const int rbase = (f * 16 + l15) * KD;
            const bf16x8 kf0 = *(const bf16x8*)&Kt[cur][rbase + cs0];
            const bf16x8 kf1 = *(const bf16x8*)&Kt[cur][rbase + cs1];
            f32x4 sU = {};
            sU = __builtin_amdgcn_mfma_f32_16x16x32_bf16(kf0, qf0U, sU, 0, 0, 0);
            sU = __builtin_amdgcn_mfma_f32_16x16x32_bf16(kf1, qf1U, sU, 0, 0, 0);
            svU[f] = sU;
            f32x4 sL = {};
            sL = __builtin_amdgcn_mfma_f32_16x16x32_bf16(kf0, qf0L, sL, 0, 0, 0);
            sL = __builtin_amdgcn_mfma_f32_16x16x32_bf16(kf1, qf1L, sL, 0, 0, 0);
            svL[f] = sL;
        }
        __builtin_amdgcn_s_setprio(0);

        // causal masks (diagonal tiles only; scale pre-folded into Q)
        if (kt == qtU) {
            #pragma unroll
            for (int f = 0; f < 4; ++f)
                #pragma unroll
                for (int r = 0; r < 4; ++r) {
                    const int kg = kt * 64 + f * 16 + quad * 4 + r;
                    svU[f][r] = (kg <= qgU) ? svU[f][r] : -1e30f;
                }
        }
        if (kt == qtL) {
            #pragma unroll
            for (int f = 0; f < 4; ++f)
                #pragma unroll
                for (int r = 0; r < 4; ++r) {
                    const int kg = kt * 64 + f * 16 + quad * 4 + r;
                    svL[f][r] = (kg <= qgL) ? svL[f][r] : -1e30f;
                }
        }

        // ---- online softmax (base-2) with defer-max, chain U ----
        {
            float mf[4];
            #pragma unroll
            for (int f = 0; f < 4; ++f)
                mf[f] = fmaxf(fmaxf(svU[f][0], svU[f][1]), fmaxf(svU[f][2], svU[f][3]));
            float mx = fmaxf(fmaxf(mf[0], mf[1]), fmaxf(mf[2], mf[3]));
            mx = fmaxf(mx, __shfl_xor(mx, 16));
            mx = fmaxf(mx, __shfl_xor(mx, 32));
            if (!__all(mx <= m_runU + 8.0f)) {
                const float mn = fmaxf(m_runU, mx);
                const float al = fast_exp2(m_runU - mn);
                m_runU = mn;
                #pragma unroll
                for (int t = 0; t < 4; ++t)
                    #pragma unroll
                    for (int r = 0; r < 4; ++r) oU[t][r] *= al;
                o4U[0] *= al;
            }
            #pragma unroll
            for (int f = 0; f < 4; ++f) {
                bf16x4 pk;
                #pragma unroll
                for (int r = 0; r < 4; ++r)
                    pk[r] = (__bf16)fast_exp2(svU[f][r] - m_runU);
                *(bf16x4*)&PwRowU[pwc[f]] = pk;
            }
        }
        // ---- chain L softmax (skipped on final global iter) ----
        if (actL) {
            float mf[4];
            #pragma unroll
            for (int f = 0; f < 4; ++f)
                mf[f] = fmaxf(fmaxf(svL[f][0], svL[f][1]), fmaxf(svL[f][2], svL[f][3]));
            float mx = fmaxf(fmaxf(mf[0], mf[1]), fmaxf(mf[2], mf[3]));
            mx = fmaxf(mx, __shfl_xor(mx, 16));
            mx = fmaxf(mx, __shfl_xor(mx, 32));
            if (!__all(mx <= m_runL + 8.0f)) {
                const float mn = fmaxf(m_runL, mx);
                const float al = fast_exp2(m_runL - mn);
                m_runL = mn;
                #pragma unroll
                for (int t = 0; t < 4; ++t)
                    #pragma unroll
                    for (int r = 0; r < 4; ++r) oL[t][r] *= al;
                o4L[0] *= al;
            }
            #pragma unroll
            for (int f = 0; f < 4; ++f) {
                bf16x4 pk;
                #pragma unroll
                for (int r = 0; r < 4; ++r)
                    pk[r] = (__bf16)fast_exp2(svL[f][r] - m_runL);
                *(bf16x4*)&PwRowL[pwc[f]] = pk;
            }
        }
        __asm__ volatile("s_waitcnt lgkmcnt(0)" ::: "memory");

        // ---- O^T += V^T P^T (vf shared by both chains); l via ones-MFMA ----
        __builtin_amdgcn_s_setprio(1);
        #pragma unroll
        for (int s = 0; s < 2; ++s) {
            const int cc = s ? cs1 : cs0;
            const bf16x8 pfU = *(const bf16x8*)&PwRowU[cc];
            if (actL) {
                const bf16x8 pfL = *(const bf16x8*)&PwRowL[cc];
                #pragma unroll
                for (int t = 0; t < 4; ++t) {
                    const bf16x8 vf = *(const bf16x8*)&Vt[cur][(t * 16 + l15) * KD + cc];
                    oU[t] = __builtin_amdgcn_mfma_f32_16x16x32_bf16(vf, pfU, oU[t], 0, 0, 0);
                    oL[t] = __builtin_amdgcn_mfma_f32_16x16x32_bf16(vf, pfL, oL[t], 0, 0, 0);
                }
                o4U = __builtin_amdgcn_mfma_f32_16x16x32_bf16(onesf, pfU, o4U, 0, 0, 0);
                o4L = __builtin_amdgcn_mfma_f32_16x16x32_bf16(onesf, pfL, o4L, 0, 0, 0);
            } else {
                #pragma unroll
                for (int t = 0; t < 4; ++t) {
                    const bf16x8 vf = *(const bf16x8*)&Vt[cur][(t * 16 + l15) * KD + cc];
                    oU[t] = __builtin_amdgcn_mfma_f32_16x16x32_bf16(vf, pfU, oU[t], 0, 0, 0);
                }
                o4U = __builtin_amdgcn_mfma_f32_16x16x32_bf16(onesf, pfU, o4U, 0, 0, 0);
            }
        }
        __builtin_amdgcn_s_setprio(0);

        if (pre) {
            *(us8*)&Kt[nxt][kwa]           = kp0;
            *(us8*)&Kt[nxt][kwa + 32 * KD] = kp1;
            #pragma unroll
            for (int j = 0; j < 8; ++j) {
                Vt[nxt][(dc0 * 8 + j) * KD + (vkey ^ (j << 3))] = vp0[j];
                Vt[nxt][(dc1 * 8 + j) * KD + (vkey ^ (j << 3))] = vp1[j];
            }
        }
        __asm__ volatile("s_waitcnt lgkmcnt(0)\n\ts_barrier" ::: "memory");
    }

    if (!heavy) {
        const float invL = 1.f / o4L[0];
        const float invU = 1.f / o4U[0];
        const size_t orowL = (size_t)(b * SEQ + qgL) * D_MODEL + headoff;
        const size_t orowU = (size_t)(b * SEQ + qgU) * D_MODEL + headoff;
        #pragma unroll
        for (int t = 0; t < 4; ++t) {
            bf16x4 pkL, pkU;
            #pragma unroll
            for (int r = 0; r < 4; ++r) {
                pkL[r] = (__bf16)(oL[t][r] * invL);
                pkU[r] = (__bf16)(oU[t][r] * invU);
            }
            *(bf16x4*)&Og[orowL + t * 16 + quad * 4] = pkL;
            *(bf16x4*)&Og[orowU + t * 16 + quad * 4] = pkU;
        }
    } else {
        // partial: unnormalized fp32 O + (m, l) to workspace; 128 rows/tile
        const int T = (bh * 8 + (qp - 8)) * 2 + part;
        const int rL = w * 16 + l15;
        const int rU = 64 + w * 16 + l15;
        float* wo = wso + (size_t)T * 8192;
        #pragma unroll
        for (int t = 0; t < 4; ++t) {
            *(f32x4*)&wo[(size_t)rL * 64 + t * 16 + quad * 4] = oL[t];
            *(f32x4*)&wo[(size_t)rU * 64 + t * 16 + quad * 4] = oU[t];
        }
        if (quad == 0) {
            f32x2 mlL = { m_runL, o4L[0] };
            f32x2 mlU = { m_runU, o4U[0] };
            *(f32x2*)&wsml[(size_t)(T * 128 + rL) * 2] = mlL;
            *(f32x2*)&wsml[(size_t)(T * 128 + rU) * 2] = mlU;
        }
    }
}

// ---------------------------------------------------------------------------
// Combine the two k-split partials for heavy q-pairs (base-2 domain).
// 32768 rows x 64 dims; thread = (row, 4 dims). Heavy rows: q in [1024,2048).
// ---------------------------------------------------------------------------
__global__ __launch_bounds__(256) void attn_combine(
    const float* __restrict__ wso, const float* __restrict__ wsml,
    ushort_t* __restrict__ Og)
{
    const int gid = blockIdx.x * 256 + threadIdx.x;
    const int row = gid >> 4;          // 0..32767
    const int dp  = (gid & 15) * 4;
    const int bh  = row >> 10;
    const int rr  = row & 1023;        // row within heavy region
    const int qph = rr >> 7;           // heavy pair index 0..7 (qp = 8+qph)
    const int q   = rr & 127;
    const int T0  = (bh * 8 + qph) * 2;

    const f32x2 ml0 = *(const f32x2*)&wsml[(size_t)(T0 * 128 + q) * 2];
    const f32x2 ml1 = *(const f32x2*)&wsml[(size_t)((T0 + 1) * 128 + q) * 2];
    const float M  = fmaxf(ml0[0], ml1[0]);
    const float a0 = fast_exp2(ml0[0] - M);
    const float a1 = fast_exp2(ml1[0] - M);
    const float inv = 1.0f / (ml0[1] * a0 + ml1[1] * a1);

    const f32x4 o0 = *(const f32x4*)&wso[(size_t)T0 * 8192 + q * 64 + dp];
    const f32x4 o1 = *(const f32x4*)&wso[(size_t)(T0 + 1) * 8192 + q * 64 + dp];

    const int b = bh >> 4;
    const int h = bh & 15;
    const int qg = 1024 + rr;          // q-rows [1024, 2048)
    bf16x4 pk;
    #pragma unroll
    for (int r = 0; r < 4; ++r)
        pk[r] = (__bf16)((o0[r] * a0 + o1[r] * a1) * inv);
    *(bf16x4*)&Og[(size_t)(b * SEQ + qg) * D_MODEL + h * DHEAD + dp] = pk;
}

// ---------------------------------------------------------------------------
// LayerNorm over last dim (1024), one block per row, fp32 in/out (in-place ok).
// ---------------------------------------------------------------------------
__global__ __launch_bounds__(256) void ln_kernel(
    const float* __restrict__ X, const float* __restrict__ g,
    const float* __restrict__ bta, float* __restrict__ out)
{
    __shared__ float r1[4], r2[4];
    const int row = blockIdx.x;
    const int tid = threadIdx.x;
    const float* p = X + (size_t)row * D_MODEL;
    float v[4]; float s1 = 0.f, s2 = 0.f;
    #pragma unroll
    for (int i = 0; i < 4; ++i) { v[i] = p[tid + 256 * i]; s1 += v[i]; s2 += v[i] * v[i]; }
    #pragma unroll
    for (int d = 32; d >= 1; d >>= 1) { s1 += __shfl_xor(s1, d); s2 += __shfl_xor(s2, d); }
    if ((tid & 63) == 0) { r1[tid >> 6] = s1; r2[tid >> 6] = s2; }
    __syncthreads();
    s1 = r1[0] + r1[1] + r1[2] + r1[3];
    s2 = r2[0] + r2[1] + r2[2] + r2[3];
    const float mu  = s1 * (1.f / D_MODEL);
    const float var = s2 * (1.f / D_MODEL) - mu * mu;
    const float rstd = rsqrtf(var + 1e-5f);
    #pragma unroll
    for (int i = 0; i < 4; ++i) {
        const int c = tid + 256 * i;
        out[(size_t)row * D_MODEL + c] = (v[i] - mu) * rstd * g[c] + bta[c];
    }
}

extern "C" void kernel_launch(void* const* d_in, const int* in_sizes, int n_in,
                              void* d_out, int out_size, void* d_ws, size_t ws_size,
                              hipStream_t stream) {
    const float* x     = (const float*)d_in[0];
    const float* Wq    = (const float*)d_in[1];
    const float* bq    = (const float*)d_in[2];
    const float* Wk    = (const float*)d_in[3];
    const float* bk    = (const float*)d_in[4];
    const float* Wv    = (const float*)d_in[5];
    const float* bv    = (const float*)d_in[6];
    const float* Wo    = (const float*)d_in[7];
    const float* bo    = (const float*)d_in[8];
    const float* gamma = (const float*)d_in[9];
    const float* beta  = (const float*)d_in[10];

    const size_t XN = (size_t)MROWS * D_MODEL;      // 4 Mi elements
    const size_t WN = (size_t)D_MODEL * D_MODEL;    // 1 Mi elements
    ushort_t* wsp = (ushort_t*)d_ws;
    ushort_t* xb  = wsp;
    ushort_t* Yq  = wsp + XN;
    ushort_t* Yk  = wsp + 2 * XN;
    ushort_t* Yv  = wsp + 3 * XN;
    ushort_t* Wqb = wsp + 4 * XN;
    ushort_t* Wkb = Wqb + WN;
    ushort_t* Wvb = Wkb + WN;
    ushort_t* Wob = Wvb + WN;
    ushort_t* ctx = xb;                 // overlay: xb dead after QKV gemm
    float*    pre = (float*)d_out;      // fp32 pre-LN lives in d_out; LN in-place

    // k-split partial buffers: after the bf16 region (40 MB).
    // wso: 512 tiles x 128 q x 64 d fp32 = 16 MB; wsml: 512 x 128 x {m,l} = 512 KB.
    float* wso  = (float*)(wsp + 4 * XN + 4 * WN);
    float* wsml = wso + (size_t)512 * 8192;

    cvt_kernel<<<dim3(4096), 256, 0, stream>>>(x, Wq, Wk, Wv, Wo, xb, Wqb, Wkb, Wvb, Wob);

    gemm_nt<ushort_t, false, 128, 128><<<dim3(MROWS / 128, D_MODEL / 128, 3), 256, 0, stream>>>(
        xb, Wqb, Wkb, Wvb, bq, bk, bv, nullptr, Yq, Yk, Yv, QSCALE);

    attn_kernel<<<dim3(BATCH * NHEADS, 24), 256, 0, stream>>>(Yq, Yk, Yv, ctx, wso, wsml);

    attn_combine<<<dim3(2048), 256, 0, stream>>>(wso, wsml, ctx);

    gemm_nt<float, true, 64, 128><<<dim3(MROWS / 64, D_MODEL / 128, 1), 256, 0, stream>>>(
        ctx, Wob, Wob, Wob, bo, bo, bo, x, pre, pre, pre, 1.0f);

    ln_kernel<<<dim3(MROWS), 256, 0, stream>>>(pre, gamma, beta, (float*)d_out);
}